// Round 12
// baseline (246.908 us; speedup 1.0000x reference)
//
#include <hip/hip_runtime.h>
#include <math.h>

typedef __attribute__((ext_vector_type(8))) short short8v;
typedef __attribute__((ext_vector_type(4))) float float4v;

constexpr float THETA = 6.28318530717958647692f / 64.0f;  // 2*pi/64

// strides in floats for layout [b][m][n][z][c], c=32
constexpr int S_B = 64 * 64 * 64 * 32;
constexpr int S_M = 64 * 64 * 32;
constexpr int S_N = 64 * 32;
constexpr int S_Z = 32;

// Native bf16 conversion (RNE) — compiler lowers pairs to v_cvt_pk_bf16_f32.
__device__ __forceinline__ unsigned short f2bf(float f) {
    __bf16 h = (__bf16)f;
    return __builtin_bit_cast(unsigned short, h);
}
__device__ __forceinline__ unsigned int pkbf(float lo, float hi) {
    return (unsigned int)f2bf(lo) | ((unsigned int)f2bf(hi) << 16);
}
__device__ __forceinline__ float bf2f(unsigned int h) {
    return __builtin_bit_cast(float, h << 16);
}

// ---------------------------------------------------------------------------
// ws fragment layout (ushort units) — unchanged:
//   Wf: [ax 3][k 16][wt 2 (0=wr,1=wi)][rt 2][lane 64][e 8]   @ 0        (98304)
//   Tf: [jt 2][s 2][lane][e]                                  @ 98304    (2048)
//   Ti: [mt 4][lane][e]                                       @ 100352   (2048)
// k-slot convention everywhere: k = 8*(lane>>4) + e (A and B share bijection).
// ---------------------------------------------------------------------------
constexpr int WS_TF = 98304, WS_TI = 100352, WS_TOTAL = 102400;

__global__ __launch_bounds__(256)
void setup_frags(const float* __restrict__ wx, const float* __restrict__ wy,
                 const float* __restrict__ wz, unsigned short* __restrict__ W)
{
    int f0 = (blockIdx.x * 256 + threadIdx.x) * 4;
#pragma unroll
    for (int u = 0; u < 4; ++u) {
        int f = f0 + u;
        if (f >= WS_TOTAL) continue;
        unsigned short v;
        if (f < WS_TF) {
            int ax = f >> 15, rem = f & 32767;
            int k = rem >> 11;
            int rem2 = rem & 2047;
            int wt = rem2 >> 10, rt = (rem2 >> 9) & 1, l = (rem2 >> 3) & 63, e = rem2 & 7;
            int o = 16 * rt + (l & 15), i = 8 * (l >> 4) + e;
            const float* w = (ax == 0) ? wx : ((ax == 1) ? wy : wz);
            v = f2bf(w[((i * 32 + o) * 16 + k) * 2 + wt]);
        } else if (f < WS_TI) {
            int rem = f - WS_TF;
            int jt = rem >> 10, s = (rem >> 9) & 1, l = (rem >> 3) & 63, e = rem & 7;
            int kk = l & 15, m = 32 * s + 8 * (l >> 4) + e;
            int jm = (kk * m) & 63;
            float ang = THETA * (float)jm;
            v = f2bf(jt == 0 ? cosf(ang) : sinf(ang));
        } else {
            int rem = f - WS_TI;
            int mt = rem >> 9, l = (rem >> 3) & 63, e = rem & 7;
            int mp = 16 * mt + (l & 15), r = 8 * (l >> 4) + e;
            int k = r & 15;
            float sk = (k == 0) ? (1.0f / 64.0f) : (2.0f / 64.0f);
            int jm = (k * mp) & 63;
            float ang = THETA * (float)jm;
            v = f2bf(r < 16 ? sk * cosf(ang) : -sk * sinf(ang));
        }
        W[f] = v;
    }
}

// AB: [t 2][k 16][line 4][i 32] bf16, 64-B rows, XOR swizzle (bijective).
constexpr int AB_SHORTS = 4096;   // 8 KB
__device__ __forceinline__ int ab4(int t, int k, int line, int i) {
    return ((((t * 16 + k) * 4 + line) * 64) + i * 2) ^ (((line ^ k) & 7) << 4);
}
// P: [line 4][o 32][r 40] ushort, line stride 1288 (strides not 0 mod 128 B).
constexpr int P_LS = 1288;
constexpr int P_SHORTS = 4 * P_LS;  // 5152
__device__ __forceinline__ int p4(int line, int o, int r) {
    return line * P_LS + o * 40 + r;
}

// ---- stage F: forward transform, 1 line per wave, A = x direct from global ----
template <int STRIDE>
__device__ __forceinline__ void stageF1(const float* __restrict__ x, long bs,
                                        const unsigned short* __restrict__ tf,
                                        unsigned short* __restrict__ AB,
                                        int lane, int line)
{
    const int gq = lane >> 4, c = lane & 15;
    short8v tfB[2][2];
#pragma unroll
    for (int jt = 0; jt < 2; ++jt)
#pragma unroll
        for (int s = 0; s < 2; ++s)
            tfB[jt][s] = *reinterpret_cast<const short8v*>(tf + ((jt * 2 + s) * 64 + lane) * 8);

    float4v acc[2][2];
#pragma unroll
    for (int rt = 0; rt < 2; ++rt)
#pragma unroll
        for (int jt = 0; jt < 2; ++jt)
            acc[rt][jt] = float4v{0.f, 0.f, 0.f, 0.f};

#pragma unroll
    for (int rt = 0; rt < 2; ++rt) {
        const float* xp = x + bs + 16 * rt + c;
#pragma unroll
        for (int s = 0; s < 2; ++s) {
            short8v a;
#pragma unroll
            for (int e = 0; e < 8; ++e)
                a[e] = (short)f2bf(xp[(long)(32 * s + 8 * gq + e) * STRIDE]);
            acc[rt][0] = __builtin_amdgcn_mfma_f32_16x16x32_bf16(a, tfB[0][s], acc[rt][0], 0, 0, 0);
            acc[rt][1] = __builtin_amdgcn_mfma_f32_16x16x32_bf16(a, tfB[1][s], acc[rt][1], 0, 0, 0);
        }
    }
#pragma unroll
    for (int rt = 0; rt < 2; ++rt)
#pragma unroll
        for (int jt = 0; jt < 2; ++jt) {
            *reinterpret_cast<uint2*>(reinterpret_cast<char*>(AB) + ab4(jt, c, line, 16 * rt + 4 * gq)) =
                make_uint2(pkbf(acc[rt][jt][0], acc[rt][jt][1]), pkbf(acc[rt][jt][2], acc[rt][jt][3]));
        }
}

// ---- stage Mx: complex channel mixing; wave owns (Pr/Pi, o-half) quadrant ----
__device__ __forceinline__ void stageMx4(const unsigned short* __restrict__ wf,
                                         const unsigned short* __restrict__ AB,
                                         unsigned short* __restrict__ P,
                                         int lane, int wave)
{
    const int gq = lane >> 4, c = lane & 15;
    const int t2 = wave >> 1, rt = wave & 1, lc = c & 3;
    for (int k = 0; k < 16; k += 2) {
        float4v acc2[2];
#pragma unroll
        for (int kk = 0; kk < 2; ++kk) {
            const int kc = k + kk;
            short8v aT = *reinterpret_cast<const short8v*>(reinterpret_cast<const char*>(AB) + ab4(0, kc, lc, 8 * gq));
            short8v bT = *reinterpret_cast<const short8v*>(reinterpret_cast<const char*>(AB) + ab4(1, kc, lc, 8 * gq));
            const int w1t = t2 ? 1 : 0, w2t = t2 ? 0 : 1;
            short8v w1 = *reinterpret_cast<const short8v*>(wf + (((kc * 2 + w1t) * 2 + rt) * 64 + lane) * 8);
            short8v w2 = *reinterpret_cast<const short8v*>(wf + (((kc * 2 + w2t) * 2 + rt) * 64 + lane) * 8);
            if (t2) {
                union { short8v s; unsigned int u[4]; } nb;
                nb.s = bT;
#pragma unroll
                for (int j = 0; j < 4; ++j) nb.u[j] ^= 0x80008000u;
                bT = nb.s;
            }
            float4v a2 = float4v{0.f, 0.f, 0.f, 0.f};
            a2 = __builtin_amdgcn_mfma_f32_16x16x32_bf16(w1, aT, a2, 0, 0, 0);
            a2 = __builtin_amdgcn_mfma_f32_16x16x32_bf16(w2, bT, a2, 0, 0, 0);
            acc2[kk] = a2;
        }
        if (c < 4) {
#pragma unroll
            for (int r = 0; r < 4; ++r) {
                *reinterpret_cast<unsigned int*>(&P[p4(c, 16 * rt + 4 * gq + r, 16 * t2 + k)]) =
                    pkbf(acc2[0][r], acc2[1][r]);
            }
        }
    }
}

// ---------------------------------------------------------------------------
// Spectral kernel (axes M, N). 4 lines/block, ~18.5 KB LDS. (unchanged)
// MODE: 0 = store f32 to out, 1 = accum f32 in out,
//       2 = store bf16 to pw,  3 = accum bf16 in pw.
// ---------------------------------------------------------------------------
template <int AXIS, int MODE>
__global__ __launch_bounds__(256)
void spectral_mfma(const float* __restrict__ x,
                   const unsigned short* __restrict__ wf,
                   const unsigned short* __restrict__ tf,
                   const unsigned short* __restrict__ ti,
                   float* __restrict__ out,
                   unsigned short* __restrict__ pw)
{
    __shared__ __align__(16) unsigned short AB[AB_SHORTS];
    __shared__ __align__(16) unsigned short P[P_SHORTS];

    const int t = threadIdx.x, lane = t & 63, wave = t >> 6;
    const int gq = lane >> 4, c = lane & 15;
    constexpr int stride = (AXIS == 0) ? S_M : S_N;

    const int l = blockIdx.x * 4 + wave;
    const int b = l >> 12, p1 = (l >> 6) & 63, p2 = l & 63;
    const long bs = (AXIS == 0)
        ? (long)b * S_B + (long)p1 * S_N + (long)p2 * S_Z
        : (long)b * S_B + (long)p1 * S_M + (long)p2 * S_Z;

    stageF1<stride>(x, bs, tf, AB, lane, wave);
    __syncthreads();
    stageMx4(wf, AB, P, lane, wave);
    __syncthreads();

    short8v tiB[4];
#pragma unroll
    for (int mt = 0; mt < 4; ++mt)
        tiB[mt] = *reinterpret_cast<const short8v*>(ti + (mt * 64 + lane) * 8);

    short8v pA[2];
    pA[0] = *reinterpret_cast<const short8v*>(&P[p4(wave, c, 8 * gq)]);
    pA[1] = *reinterpret_cast<const short8v*>(&P[p4(wave, 16 + c, 8 * gq)]);

#pragma unroll
    for (int rt = 0; rt < 2; ++rt)
#pragma unroll
        for (int mt = 0; mt < 4; ++mt) {
            float4v acc = float4v{0.f, 0.f, 0.f, 0.f};
            acc = __builtin_amdgcn_mfma_f32_16x16x32_bf16(pA[rt], tiB[mt], acc, 0, 0, 0);
            const long off = bs + (long)(16 * mt + c) * stride + 16 * rt + 4 * gq;
            if (MODE == 0) {
                *reinterpret_cast<float4*>(out + off) = make_float4(acc[0], acc[1], acc[2], acc[3]);
            } else if (MODE == 1) {
                float4 old = *reinterpret_cast<const float4*>(out + off);
                old.x += acc[0]; old.y += acc[1]; old.z += acc[2]; old.w += acc[3];
                *reinterpret_cast<float4*>(out + off) = old;
            } else if (MODE == 2) {
                *reinterpret_cast<uint2*>(pw + off) =
                    make_uint2(pkbf(acc[0], acc[1]), pkbf(acc[2], acc[3]));
            } else {
                uint2 old = *reinterpret_cast<const uint2*>(pw + off);
                const float v0 = bf2f(old.x & 0xffffu) + acc[0];
                const float v1 = bf2f(old.x >> 16)     + acc[1];
                const float v2 = bf2f(old.y & 0xffffu) + acc[2];
                const float v3 = bf2f(old.y >> 16)     + acc[3];
                *reinterpret_cast<uint2*>(pw + off) =
                    make_uint2(pkbf(v0, v1), pkbf(v2, v3));
            }
        }
}

// ---------------------------------------------------------------------------
// Fused axis-Z spectral + FFN + LayerNorm — round-8 structure PLUS hoisted
// partial loads (T14 issue-early): all pw1/pw2 reads are issued at kernel
// entry, hidden under stage F + Mx (~2 barriers away), consumed in stage I.
// Regions (shorts):
//   [0,8192)       AB (4096 used) -> (after Mx) FFN weight fragments
//   [8192,13344)   P  (pitch 1288, own region)
//   [13344,23584)  S tile [line 4][pt 64][ch pad 40]; per-wave H overlays
//                  its OWN S slab (consumed into af[] regs before H writes).
// NPART: 0 = f32 partial in out; 1 = one bf16 partial; 2 = two bf16 partials.
// ---------------------------------------------------------------------------
template <int NPART>
__global__ __launch_bounds__(256)
void spectral_fused(const float* __restrict__ x,
                    const unsigned short* __restrict__ wf,
                    const unsigned short* __restrict__ tf,
                    const unsigned short* __restrict__ ti,
                    const float* __restrict__ w0, const float* __restrict__ b0,
                    const float* __restrict__ w1, const float* __restrict__ b1,
                    const float* __restrict__ g,  const float* __restrict__ bb,
                    const unsigned short* __restrict__ pw1,
                    const unsigned short* __restrict__ pw2,
                    const float* __restrict__ pf32,
                    float* __restrict__ out)
{
    __shared__ __align__(16) unsigned short sm[23584];
    constexpr int OP = 8192, OS = 13344;

    const int t = threadIdx.x, lane = t & 63, wave = t >> 6;
    const int gq = lane >> 4, c = lane & 15;

    const int l = blockIdx.x * 4 + wave;
    const int b = l >> 12, p1 = (l >> 6) & 63, p2 = l & 63;
    const long bs = (long)b * S_B + (long)p1 * S_M + (long)p2 * S_N;

    // ---- HOISTED partial loads: issue 8-16 independent global loads NOW;
    //      stage F + Mx (two barriers of compute) hide their latency. ----
    uint2 hv1[2][4], hv2[2][4];
    if (NPART >= 1) {
#pragma unroll
        for (int rt = 0; rt < 2; ++rt)
#pragma unroll
            for (int mt = 0; mt < 4; ++mt) {
                const long off = bs + (long)(16 * mt + c) * S_Z + 16 * rt + 4 * gq;
                hv1[rt][mt] = *reinterpret_cast<const uint2*>(pw1 + off);
                if (NPART == 2)
                    hv2[rt][mt] = *reinterpret_cast<const uint2*>(pw2 + off);
            }
    }

    float4 b0q[8];
#pragma unroll
    for (int n = 0; n < 8; ++n)
        b0q[n] = *reinterpret_cast<const float4*>(b0 + 16 * n + 4 * gq);
    float b1v[2], gv[2], bvv[2];
#pragma unroll
    for (int n = 0; n < 2; ++n) { b1v[n] = b1[n * 16 + c]; gv[n] = g[n * 16 + c]; bvv[n] = bb[n * 16 + c]; }

    stageF1<S_Z>(x, bs, tf, sm, lane, wave);
    __syncthreads();
    stageMx4(wf, sm, sm + OP, lane, wave);
    __syncthreads();

    // ---- FFN weight fragments into dead AB region ----
    for (int s = t; s < 512; s += 256) {
        const int n = s >> 6, ln = s & 63, g2 = ln >> 4, c2 = ln & 15;
        const int kb = n >> 1, nn = n & 1;
        short8v v0, v1;
#pragma unroll
        for (int e = 0; e < 8; ++e) {
            v0[e] = (short)f2bf(w0[(8 * g2 + e) * 128 + n * 16 + c2]);
            v1[e] = (short)f2bf(w1[(32 * kb + 8 * g2 + e) * 32 + nn * 16 + c2]);
        }
        *reinterpret_cast<short8v*>(&sm[s * 8])        = v0;
        *reinterpret_cast<short8v*>(&sm[4096 + s * 8]) = v1;
    }

    // ---- stage I: S = partial(xx+xy) + axis-z result, bf16 in LDS ----
    short8v tiB[4];
#pragma unroll
    for (int mt = 0; mt < 4; ++mt)
        tiB[mt] = *reinterpret_cast<const short8v*>(ti + (mt * 64 + lane) * 8);

    {
        short8v pA[2];
        pA[0] = *reinterpret_cast<const short8v*>(&sm[OP + p4(wave, c, 8 * gq)]);
        pA[1] = *reinterpret_cast<const short8v*>(&sm[OP + p4(wave, 16 + c, 8 * gq)]);
#pragma unroll
        for (int rt = 0; rt < 2; ++rt)
#pragma unroll
            for (int mt = 0; mt < 4; ++mt) {
                float4v acc = float4v{0.f, 0.f, 0.f, 0.f};
                acc = __builtin_amdgcn_mfma_f32_16x16x32_bf16(pA[rt], tiB[mt], acc, 0, 0, 0);
                float v0, v1, v2, v3;
                if (NPART == 0) {
                    const long off = bs + (long)(16 * mt + c) * S_Z + 16 * rt + 4 * gq;
                    float4 old = *reinterpret_cast<const float4*>(pf32 + off);
                    v0 = old.x + acc[0]; v1 = old.y + acc[1];
                    v2 = old.z + acc[2]; v3 = old.w + acc[3];
                } else {
                    const uint2 pv = hv1[rt][mt];
                    v0 = bf2f(pv.x & 0xffffu) + acc[0];
                    v1 = bf2f(pv.x >> 16)     + acc[1];
                    v2 = bf2f(pv.y & 0xffffu) + acc[2];
                    v3 = bf2f(pv.y >> 16)     + acc[3];
                    if (NPART == 2) {
                        const uint2 qv = hv2[rt][mt];
                        v0 += bf2f(qv.x & 0xffffu);
                        v1 += bf2f(qv.x >> 16);
                        v2 += bf2f(qv.y & 0xffffu);
                        v3 += bf2f(qv.y >> 16);
                    }
                }
                const int si = OS + (wave * 64 + 16 * mt + c) * 40 + 16 * rt + 4 * gq;
                *reinterpret_cast<uint2*>(&sm[si]) = make_uint2(pkbf(v0, v1), pkbf(v2, v3));
            }
    }
    __syncthreads();

    // ---- FFN + LN, 1 tile per wave; H overlays own S slab ----
    const int Hb = OS + wave * 2560;

    short8v af[4];
#pragma unroll
    for (int f = 0; f < 4; ++f)
        af[f] = *reinterpret_cast<const short8v*>(&sm[OS + (wave * 64 + 16 * f + c) * 40 + 8 * gq]);

    float4v Y[4][2];
#pragma unroll
    for (int f = 0; f < 4; ++f)
#pragma unroll
        for (int n = 0; n < 2; ++n)
            Y[f][n] = float4v{b1v[n], b1v[n], b1v[n], b1v[n]};

#pragma unroll
    for (int kb = 0; kb < 4; ++kb) {
        // GEMM1 (swapped): D rows = hidden j = 16nn+4gq+r, col = point 16f+c
#pragma unroll
        for (int nn = 0; nn < 2; ++nn) {
            const int n = 2 * kb + nn;
            const short8v wv = *reinterpret_cast<const short8v*>(&sm[(n * 64 + lane) * 8]);
#pragma unroll
            for (int f = 0; f < 4; ++f) {
                float4v hacc = float4v{b0q[n].x, b0q[n].y, b0q[n].z, b0q[n].w};
                hacc = __builtin_amdgcn_mfma_f32_16x16x32_bf16(wv, af[f], hacc, 0, 0, 0);
                const float h0 = fmaxf(hacc[0], 0.f), h1 = fmaxf(hacc[1], 0.f);
                const float h2 = fmaxf(hacc[2], 0.f), h3 = fmaxf(hacc[3], 0.f);
                *reinterpret_cast<uint2*>(&sm[Hb + (16 * f + c) * 40 + 16 * nn + 4 * gq]) =
                    make_uint2(pkbf(h0, h1), pkbf(h2, h3));
            }
        }
        const short8v wva = *reinterpret_cast<const short8v*>(&sm[4096 + ((kb * 2 + 0) * 64 + lane) * 8]);
        const short8v wvb = *reinterpret_cast<const short8v*>(&sm[4096 + ((kb * 2 + 1) * 64 + lane) * 8]);
#pragma unroll
        for (int f = 0; f < 4; ++f) {
            const short8v a2 = *reinterpret_cast<const short8v*>(&sm[Hb + (16 * f + c) * 40 + 8 * gq]);
            Y[f][0] = __builtin_amdgcn_mfma_f32_16x16x32_bf16(a2, wva, Y[f][0], 0, 0, 0);
            Y[f][1] = __builtin_amdgcn_mfma_f32_16x16x32_bf16(a2, wvb, Y[f][1], 0, 0, 0);
        }
    }

#pragma unroll
    for (int f = 0; f < 4; ++f) {
        float smv[4], sq[4];
#pragma unroll
        for (int r = 0; r < 4; ++r) {
            const float v0 = Y[f][0][r], v1 = Y[f][1][r];
            smv[r] = v0 + v1;
            sq[r]  = v0 * v0 + v1 * v1;
        }
#pragma unroll
        for (int mask = 1; mask <= 8; mask <<= 1) {
#pragma unroll
            for (int r = 0; r < 4; ++r) {
                smv[r] += __shfl_xor(smv[r], mask);
                sq[r]  += __shfl_xor(sq[r], mask);
            }
        }
#pragma unroll
        for (int r = 0; r < 4; ++r) {
            const float mu = smv[r] * (1.0f / 32.0f);
            const float var = sq[r] * (1.0f / 32.0f) - mu * mu;
            const float rs = rsqrtf(var + 1e-5f);
            float* op = out + bs + (long)(16 * f + 4 * gq + r) * 32;
            op[c]      = (Y[f][0][r] - mu) * rs * gv[0] + bvv[0];
            op[16 + c] = (Y[f][1][r] - mu) * rs * gv[1] + bvv[1];
        }
    }
}

extern "C" void kernel_launch(void* const* d_in, const int* in_sizes, int n_in,
                              void* d_out, int out_size, void* d_ws, size_t ws_size,
                              hipStream_t stream)
{
    const float* x    = (const float*)d_in[0];
    const float* wx   = (const float*)d_in[1];
    const float* wy   = (const float*)d_in[2];
    const float* wz   = (const float*)d_in[3];
    const float* w0   = (const float*)d_in[4];
    const float* b0   = (const float*)d_in[5];
    const float* w1   = (const float*)d_in[6];
    const float* b1   = (const float*)d_in[7];
    const float* ln_g = (const float*)d_in[8];
    const float* ln_b = (const float*)d_in[9];
    float* out = (float*)d_out;

    unsigned short* wsf = (unsigned short*)d_ws;

    const size_t PART_OFF   = 262144;                 // frag region < 256 KB
    const size_t PART_BYTES = (size_t)33554432 * 2;   // 64 MB bf16 partial
    unsigned short* pw1 = (unsigned short*)((char*)d_ws + PART_OFF);
    unsigned short* pw2 = (unsigned short*)((char*)d_ws + PART_OFF + PART_BYTES);
    const int tier = (ws_size >= PART_OFF + 2 * PART_BYTES) ? 2
                   : (ws_size >= PART_OFF + PART_BYTES)     ? 1 : 0;

    setup_frags<<<100, 256, 0, stream>>>(wx, wy, wz, wsf);

    // 16384 lines per axis / 4 per block = 4096 blocks
    if (tier == 2) {
        spectral_mfma<0, 2><<<4096, 256, 0, stream>>>(x, wsf + 0 * 32768, wsf + WS_TF, wsf + WS_TI, out, pw1);
        spectral_mfma<1, 2><<<4096, 256, 0, stream>>>(x, wsf + 1 * 32768, wsf + WS_TF, wsf + WS_TI, out, pw2);
        spectral_fused<2><<<4096, 256, 0, stream>>>(x, wsf + 2 * 32768, wsf + WS_TF, wsf + WS_TI,
                                                    w0, b0, w1, b1, ln_g, ln_b, pw1, pw2, out, out);
    } else if (tier == 1) {
        spectral_mfma<0, 2><<<4096, 256, 0, stream>>>(x, wsf + 0 * 32768, wsf + WS_TF, wsf + WS_TI, out, pw1);
        spectral_mfma<1, 3><<<4096, 256, 0, stream>>>(x, wsf + 1 * 32768, wsf + WS_TF, wsf + WS_TI, out, pw1);
        spectral_fused<1><<<4096, 256, 0, stream>>>(x, wsf + 2 * 32768, wsf + WS_TF, wsf + WS_TI,
                                                    w0, b0, w1, b1, ln_g, ln_b, pw1, pw1, out, out);
    } else {
        spectral_mfma<0, 0><<<4096, 256, 0, stream>>>(x, wsf + 0 * 32768, wsf + WS_TF, wsf + WS_TI, out, pw1);
        spectral_mfma<1, 1><<<4096, 256, 0, stream>>>(x, wsf + 1 * 32768, wsf + WS_TF, wsf + WS_TI, out, pw1);
        spectral_fused<0><<<4096, 256, 0, stream>>>(x, wsf + 2 * 32768, wsf + WS_TF, wsf + WS_TI,
                                                    w0, b0, w1, b1, ln_g, ln_b, pw1, pw1, out, out);
    }
}

// Round 13
// 220.578 us; speedup vs baseline: 1.1194x; 1.1194x over previous
//
#include <hip/hip_runtime.h>
#include <math.h>

typedef __attribute__((ext_vector_type(8))) short short8v;
typedef __attribute__((ext_vector_type(4))) float float4v;

constexpr float THETA = 6.28318530717958647692f / 64.0f;  // 2*pi/64

// strides in floats for layout [b][m][n][z][c], c=32
constexpr int S_B = 64 * 64 * 64 * 32;
constexpr int S_M = 64 * 64 * 32;
constexpr int S_N = 64 * 32;
constexpr int S_Z = 32;

// Native bf16 conversion (RNE) — compiler lowers pairs to v_cvt_pk_bf16_f32.
__device__ __forceinline__ unsigned short f2bf(float f) {
    __bf16 h = (__bf16)f;
    return __builtin_bit_cast(unsigned short, h);
}
__device__ __forceinline__ unsigned int pkbf(float lo, float hi) {
    return (unsigned int)f2bf(lo) | ((unsigned int)f2bf(hi) << 16);
}
__device__ __forceinline__ float bf2f(unsigned int h) {
    return __builtin_bit_cast(float, h << 16);
}

// ---------------------------------------------------------------------------
// ws fragment layout (ushort units) — unchanged:
//   Wf: [ax 3][k 16][wt 2 (0=wr,1=wi)][rt 2][lane 64][e 8]   @ 0        (98304)
//   Tf: [jt 2][s 2][lane][e]                                  @ 98304    (2048)
//   Ti: [mt 4][lane][e]                                       @ 100352   (2048)
// k-slot convention everywhere: k = 8*(lane>>4) + e (A and B share bijection).
// ---------------------------------------------------------------------------
constexpr int WS_TF = 98304, WS_TI = 100352, WS_TOTAL = 102400;

__global__ __launch_bounds__(256)
void setup_frags(const float* __restrict__ wx, const float* __restrict__ wy,
                 const float* __restrict__ wz, unsigned short* __restrict__ W)
{
    int f0 = (blockIdx.x * 256 + threadIdx.x) * 4;
#pragma unroll
    for (int u = 0; u < 4; ++u) {
        int f = f0 + u;
        if (f >= WS_TOTAL) continue;
        unsigned short v;
        if (f < WS_TF) {
            int ax = f >> 15, rem = f & 32767;
            int k = rem >> 11;
            int rem2 = rem & 2047;
            int wt = rem2 >> 10, rt = (rem2 >> 9) & 1, l = (rem2 >> 3) & 63, e = rem2 & 7;
            int o = 16 * rt + (l & 15), i = 8 * (l >> 4) + e;
            const float* w = (ax == 0) ? wx : ((ax == 1) ? wy : wz);
            v = f2bf(w[((i * 32 + o) * 16 + k) * 2 + wt]);
        } else if (f < WS_TI) {
            int rem = f - WS_TF;
            int jt = rem >> 10, s = (rem >> 9) & 1, l = (rem >> 3) & 63, e = rem & 7;
            int kk = l & 15, m = 32 * s + 8 * (l >> 4) + e;
            int jm = (kk * m) & 63;
            float ang = THETA * (float)jm;
            v = f2bf(jt == 0 ? cosf(ang) : sinf(ang));
        } else {
            int rem = f - WS_TI;
            int mt = rem >> 9, l = (rem >> 3) & 63, e = rem & 7;
            int mp = 16 * mt + (l & 15), r = 8 * (l >> 4) + e;
            int k = r & 15;
            float sk = (k == 0) ? (1.0f / 64.0f) : (2.0f / 64.0f);
            int jm = (k * mp) & 63;
            float ang = THETA * (float)jm;
            v = f2bf(r < 16 ? sk * cosf(ang) : -sk * sinf(ang));
        }
        W[f] = v;
    }
}

// AB: [t 2][k 16][line 4][i 32] bf16, 64-B rows, XOR swizzle (bijective).
constexpr int AB_SHORTS = 4096;   // 8 KB
__device__ __forceinline__ int ab4(int t, int k, int line, int i) {
    return ((((t * 16 + k) * 4 + line) * 64) + i * 2) ^ (((line ^ k) & 7) << 4);
}
// P: [line 4][o 32][r 40] ushort, line stride 1288 (strides not 0 mod 128 B).
constexpr int P_LS = 1288;
constexpr int P_SHORTS = 4 * P_LS;  // 5152
__device__ __forceinline__ int p4(int line, int o, int r) {
    return line * P_LS + o * 40 + r;
}

// ---- stage F: forward transform, 1 line per wave, A = x direct from global ----
template <int STRIDE>
__device__ __forceinline__ void stageF1(const float* __restrict__ x, long bs,
                                        const unsigned short* __restrict__ tf,
                                        unsigned short* __restrict__ AB,
                                        int lane, int line)
{
    const int gq = lane >> 4, c = lane & 15;
    short8v tfB[2][2];
#pragma unroll
    for (int jt = 0; jt < 2; ++jt)
#pragma unroll
        for (int s = 0; s < 2; ++s)
            tfB[jt][s] = *reinterpret_cast<const short8v*>(tf + ((jt * 2 + s) * 64 + lane) * 8);

    float4v acc[2][2];
#pragma unroll
    for (int rt = 0; rt < 2; ++rt)
#pragma unroll
        for (int jt = 0; jt < 2; ++jt)
            acc[rt][jt] = float4v{0.f, 0.f, 0.f, 0.f};

#pragma unroll
    for (int rt = 0; rt < 2; ++rt) {
        const float* xp = x + bs + 16 * rt + c;
#pragma unroll
        for (int s = 0; s < 2; ++s) {
            short8v a;
#pragma unroll
            for (int e = 0; e < 8; ++e)
                a[e] = (short)f2bf(xp[(long)(32 * s + 8 * gq + e) * STRIDE]);
            acc[rt][0] = __builtin_amdgcn_mfma_f32_16x16x32_bf16(a, tfB[0][s], acc[rt][0], 0, 0, 0);
            acc[rt][1] = __builtin_amdgcn_mfma_f32_16x16x32_bf16(a, tfB[1][s], acc[rt][1], 0, 0, 0);
        }
    }
#pragma unroll
    for (int rt = 0; rt < 2; ++rt)
#pragma unroll
        for (int jt = 0; jt < 2; ++jt) {
            *reinterpret_cast<uint2*>(reinterpret_cast<char*>(AB) + ab4(jt, c, line, 16 * rt + 4 * gq)) =
                make_uint2(pkbf(acc[rt][jt][0], acc[rt][jt][1]), pkbf(acc[rt][jt][2], acc[rt][jt][3]));
        }
}

// ---- stage Mx: complex channel mixing; wave owns (Pr/Pi, o-half) quadrant ----
__device__ __forceinline__ void stageMx4(const unsigned short* __restrict__ wf,
                                         const unsigned short* __restrict__ AB,
                                         unsigned short* __restrict__ P,
                                         int lane, int wave)
{
    const int gq = lane >> 4, c = lane & 15;
    const int t2 = wave >> 1, rt = wave & 1, lc = c & 3;
    for (int k = 0; k < 16; k += 2) {
        float4v acc2[2];
#pragma unroll
        for (int kk = 0; kk < 2; ++kk) {
            const int kc = k + kk;
            short8v aT = *reinterpret_cast<const short8v*>(reinterpret_cast<const char*>(AB) + ab4(0, kc, lc, 8 * gq));
            short8v bT = *reinterpret_cast<const short8v*>(reinterpret_cast<const char*>(AB) + ab4(1, kc, lc, 8 * gq));
            const int w1t = t2 ? 1 : 0, w2t = t2 ? 0 : 1;
            short8v w1 = *reinterpret_cast<const short8v*>(wf + (((kc * 2 + w1t) * 2 + rt) * 64 + lane) * 8);
            short8v w2 = *reinterpret_cast<const short8v*>(wf + (((kc * 2 + w2t) * 2 + rt) * 64 + lane) * 8);
            if (t2) {
                union { short8v s; unsigned int u[4]; } nb;
                nb.s = bT;
#pragma unroll
                for (int j = 0; j < 4; ++j) nb.u[j] ^= 0x80008000u;
                bT = nb.s;
            }
            float4v a2 = float4v{0.f, 0.f, 0.f, 0.f};
            a2 = __builtin_amdgcn_mfma_f32_16x16x32_bf16(w1, aT, a2, 0, 0, 0);
            a2 = __builtin_amdgcn_mfma_f32_16x16x32_bf16(w2, bT, a2, 0, 0, 0);
            acc2[kk] = a2;
        }
        if (c < 4) {
#pragma unroll
            for (int r = 0; r < 4; ++r) {
                *reinterpret_cast<unsigned int*>(&P[p4(c, 16 * rt + 4 * gq + r, 16 * t2 + k)]) =
                    pkbf(acc2[0][r], acc2[1][r]);
            }
        }
    }
}

// ---------------------------------------------------------------------------
// Spectral kernel (axes M, N). 4 lines/block, ~18.5 KB LDS. (unchanged)
// MODE: 0 = store f32 to out, 1 = accum f32 in out,
//       2 = store bf16 to pw,  3 = accum bf16 in pw.
// ---------------------------------------------------------------------------
template <int AXIS, int MODE>
__global__ __launch_bounds__(256)
void spectral_mfma(const float* __restrict__ x,
                   const unsigned short* __restrict__ wf,
                   const unsigned short* __restrict__ tf,
                   const unsigned short* __restrict__ ti,
                   float* __restrict__ out,
                   unsigned short* __restrict__ pw)
{
    __shared__ __align__(16) unsigned short AB[AB_SHORTS];
    __shared__ __align__(16) unsigned short P[P_SHORTS];

    const int t = threadIdx.x, lane = t & 63, wave = t >> 6;
    const int gq = lane >> 4, c = lane & 15;
    constexpr int stride = (AXIS == 0) ? S_M : S_N;

    const int l = blockIdx.x * 4 + wave;
    const int b = l >> 12, p1 = (l >> 6) & 63, p2 = l & 63;
    const long bs = (AXIS == 0)
        ? (long)b * S_B + (long)p1 * S_N + (long)p2 * S_Z
        : (long)b * S_B + (long)p1 * S_M + (long)p2 * S_Z;

    stageF1<stride>(x, bs, tf, AB, lane, wave);
    __syncthreads();
    stageMx4(wf, AB, P, lane, wave);
    __syncthreads();

    short8v tiB[4];
#pragma unroll
    for (int mt = 0; mt < 4; ++mt)
        tiB[mt] = *reinterpret_cast<const short8v*>(ti + (mt * 64 + lane) * 8);

    short8v pA[2];
    pA[0] = *reinterpret_cast<const short8v*>(&P[p4(wave, c, 8 * gq)]);
    pA[1] = *reinterpret_cast<const short8v*>(&P[p4(wave, 16 + c, 8 * gq)]);

#pragma unroll
    for (int rt = 0; rt < 2; ++rt)
#pragma unroll
        for (int mt = 0; mt < 4; ++mt) {
            float4v acc = float4v{0.f, 0.f, 0.f, 0.f};
            acc = __builtin_amdgcn_mfma_f32_16x16x32_bf16(pA[rt], tiB[mt], acc, 0, 0, 0);
            const long off = bs + (long)(16 * mt + c) * stride + 16 * rt + 4 * gq;
            if (MODE == 0) {
                *reinterpret_cast<float4*>(out + off) = make_float4(acc[0], acc[1], acc[2], acc[3]);
            } else if (MODE == 1) {
                float4 old = *reinterpret_cast<const float4*>(out + off);
                old.x += acc[0]; old.y += acc[1]; old.z += acc[2]; old.w += acc[3];
                *reinterpret_cast<float4*>(out + off) = old;
            } else if (MODE == 2) {
                *reinterpret_cast<uint2*>(pw + off) =
                    make_uint2(pkbf(acc[0], acc[1]), pkbf(acc[2], acc[3]));
            } else {
                uint2 old = *reinterpret_cast<const uint2*>(pw + off);
                const float v0 = bf2f(old.x & 0xffffu) + acc[0];
                const float v1 = bf2f(old.x >> 16)     + acc[1];
                const float v2 = bf2f(old.y & 0xffffu) + acc[2];
                const float v3 = bf2f(old.y >> 16)     + acc[3];
                *reinterpret_cast<uint2*>(pw + off) =
                    make_uint2(pkbf(v0, v1), pkbf(v2, v3));
            }
        }
}

// ---------------------------------------------------------------------------
// Fused axis-Z spectral + FFN + LayerNorm — EXACT round-8/11 structure
// (in-loop partial reads; both hoist variants regressed). Regions (shorts):
//   [0,8192)       AB (4096 used) -> (after Mx) FFN weight fragments
//   [8192,13344)   P  (pitch 1288, own region)
//   [13344,23584)  S tile [line 4][pt 64][ch pad 40]; per-wave H overlays
//                  its OWN S slab (consumed into af[] regs before H writes).
// NPART: 0 = f32 partial in out; 1 = one bf16 partial (SCHEDULE DEFAULT —
// single pw keeps fused's 192 MB read set L3-resident behind axis1's RMW).
// ---------------------------------------------------------------------------
template <int NPART>
__global__ __launch_bounds__(256)
void spectral_fused(const float* __restrict__ x,
                    const unsigned short* __restrict__ wf,
                    const unsigned short* __restrict__ tf,
                    const unsigned short* __restrict__ ti,
                    const float* __restrict__ w0, const float* __restrict__ b0,
                    const float* __restrict__ w1, const float* __restrict__ b1,
                    const float* __restrict__ g,  const float* __restrict__ bb,
                    const unsigned short* __restrict__ pw1,
                    const float* __restrict__ pf32,
                    float* __restrict__ out)
{
    __shared__ __align__(16) unsigned short sm[23584];
    constexpr int OP = 8192, OS = 13344;

    const int t = threadIdx.x, lane = t & 63, wave = t >> 6;
    const int gq = lane >> 4, c = lane & 15;

    const int l = blockIdx.x * 4 + wave;
    const int b = l >> 12, p1 = (l >> 6) & 63, p2 = l & 63;
    const long bs = (long)b * S_B + (long)p1 * S_M + (long)p2 * S_N;

    float4 b0q[8];
#pragma unroll
    for (int n = 0; n < 8; ++n)
        b0q[n] = *reinterpret_cast<const float4*>(b0 + 16 * n + 4 * gq);
    float b1v[2], gv[2], bvv[2];
#pragma unroll
    for (int n = 0; n < 2; ++n) { b1v[n] = b1[n * 16 + c]; gv[n] = g[n * 16 + c]; bvv[n] = bb[n * 16 + c]; }

    stageF1<S_Z>(x, bs, tf, sm, lane, wave);
    __syncthreads();
    stageMx4(wf, sm, sm + OP, lane, wave);
    __syncthreads();

    // ---- FFN weight fragments into dead AB region ----
    for (int s = t; s < 512; s += 256) {
        const int n = s >> 6, ln = s & 63, g2 = ln >> 4, c2 = ln & 15;
        const int kb = n >> 1, nn = n & 1;
        short8v v0, v1;
#pragma unroll
        for (int e = 0; e < 8; ++e) {
            v0[e] = (short)f2bf(w0[(8 * g2 + e) * 128 + n * 16 + c2]);
            v1[e] = (short)f2bf(w1[(32 * kb + 8 * g2 + e) * 32 + nn * 16 + c2]);
        }
        *reinterpret_cast<short8v*>(&sm[s * 8])        = v0;
        *reinterpret_cast<short8v*>(&sm[4096 + s * 8]) = v1;
    }

    // ---- stage I: S = partial(xx+xy) + axis-z result, bf16 in LDS ----
    short8v tiB[4];
#pragma unroll
    for (int mt = 0; mt < 4; ++mt)
        tiB[mt] = *reinterpret_cast<const short8v*>(ti + (mt * 64 + lane) * 8);

    {
        short8v pA[2];
        pA[0] = *reinterpret_cast<const short8v*>(&sm[OP + p4(wave, c, 8 * gq)]);
        pA[1] = *reinterpret_cast<const short8v*>(&sm[OP + p4(wave, 16 + c, 8 * gq)]);
#pragma unroll
        for (int rt = 0; rt < 2; ++rt)
#pragma unroll
            for (int mt = 0; mt < 4; ++mt) {
                float4v acc = float4v{0.f, 0.f, 0.f, 0.f};
                acc = __builtin_amdgcn_mfma_f32_16x16x32_bf16(pA[rt], tiB[mt], acc, 0, 0, 0);
                const long off = bs + (long)(16 * mt + c) * S_Z + 16 * rt + 4 * gq;
                float v0, v1, v2, v3;
                if (NPART == 0) {
                    float4 old = *reinterpret_cast<const float4*>(pf32 + off);
                    v0 = old.x + acc[0]; v1 = old.y + acc[1];
                    v2 = old.z + acc[2]; v3 = old.w + acc[3];
                } else {
                    uint2 pv = *reinterpret_cast<const uint2*>(pw1 + off);
                    v0 = bf2f(pv.x & 0xffffu) + acc[0];
                    v1 = bf2f(pv.x >> 16)     + acc[1];
                    v2 = bf2f(pv.y & 0xffffu) + acc[2];
                    v3 = bf2f(pv.y >> 16)     + acc[3];
                }
                const int si = OS + (wave * 64 + 16 * mt + c) * 40 + 16 * rt + 4 * gq;
                *reinterpret_cast<uint2*>(&sm[si]) = make_uint2(pkbf(v0, v1), pkbf(v2, v3));
            }
    }
    __syncthreads();

    // ---- FFN + LN, 1 tile per wave; H overlays own S slab ----
    const int Hb = OS + wave * 2560;

    short8v af[4];
#pragma unroll
    for (int f = 0; f < 4; ++f)
        af[f] = *reinterpret_cast<const short8v*>(&sm[OS + (wave * 64 + 16 * f + c) * 40 + 8 * gq]);

    float4v Y[4][2];
#pragma unroll
    for (int f = 0; f < 4; ++f)
#pragma unroll
        for (int n = 0; n < 2; ++n)
            Y[f][n] = float4v{b1v[n], b1v[n], b1v[n], b1v[n]};

#pragma unroll
    for (int kb = 0; kb < 4; ++kb) {
        // GEMM1 (swapped): D rows = hidden j = 16nn+4gq+r, col = point 16f+c
#pragma unroll
        for (int nn = 0; nn < 2; ++nn) {
            const int n = 2 * kb + nn;
            const short8v wv = *reinterpret_cast<const short8v*>(&sm[(n * 64 + lane) * 8]);
#pragma unroll
            for (int f = 0; f < 4; ++f) {
                float4v hacc = float4v{b0q[n].x, b0q[n].y, b0q[n].z, b0q[n].w};
                hacc = __builtin_amdgcn_mfma_f32_16x16x32_bf16(wv, af[f], hacc, 0, 0, 0);
                const float h0 = fmaxf(hacc[0], 0.f), h1 = fmaxf(hacc[1], 0.f);
                const float h2 = fmaxf(hacc[2], 0.f), h3 = fmaxf(hacc[3], 0.f);
                *reinterpret_cast<uint2*>(&sm[Hb + (16 * f + c) * 40 + 16 * nn + 4 * gq]) =
                    make_uint2(pkbf(h0, h1), pkbf(h2, h3));
            }
        }
        const short8v wva = *reinterpret_cast<const short8v*>(&sm[4096 + ((kb * 2 + 0) * 64 + lane) * 8]);
        const short8v wvb = *reinterpret_cast<const short8v*>(&sm[4096 + ((kb * 2 + 1) * 64 + lane) * 8]);
#pragma unroll
        for (int f = 0; f < 4; ++f) {
            const short8v a2 = *reinterpret_cast<const short8v*>(&sm[Hb + (16 * f + c) * 40 + 8 * gq]);
            Y[f][0] = __builtin_amdgcn_mfma_f32_16x16x32_bf16(a2, wva, Y[f][0], 0, 0, 0);
            Y[f][1] = __builtin_amdgcn_mfma_f32_16x16x32_bf16(a2, wvb, Y[f][1], 0, 0, 0);
        }
    }

#pragma unroll
    for (int f = 0; f < 4; ++f) {
        float smv[4], sq[4];
#pragma unroll
        for (int r = 0; r < 4; ++r) {
            const float v0 = Y[f][0][r], v1 = Y[f][1][r];
            smv[r] = v0 + v1;
            sq[r]  = v0 * v0 + v1 * v1;
        }
#pragma unroll
        for (int mask = 1; mask <= 8; mask <<= 1) {
#pragma unroll
            for (int r = 0; r < 4; ++r) {
                smv[r] += __shfl_xor(smv[r], mask);
                sq[r]  += __shfl_xor(sq[r], mask);
            }
        }
#pragma unroll
        for (int r = 0; r < 4; ++r) {
            const float mu = smv[r] * (1.0f / 32.0f);
            const float var = sq[r] * (1.0f / 32.0f) - mu * mu;
            const float rs = rsqrtf(var + 1e-5f);
            float* op = out + bs + (long)(16 * f + 4 * gq + r) * 32;
            op[c]      = (Y[f][0][r] - mu) * rs * gv[0] + bvv[0];
            op[16 + c] = (Y[f][1][r] - mu) * rs * gv[1] + bvv[1];
        }
    }
}

extern "C" void kernel_launch(void* const* d_in, const int* in_sizes, int n_in,
                              void* d_out, int out_size, void* d_ws, size_t ws_size,
                              hipStream_t stream)
{
    const float* x    = (const float*)d_in[0];
    const float* wx   = (const float*)d_in[1];
    const float* wy   = (const float*)d_in[2];
    const float* wz   = (const float*)d_in[3];
    const float* w0   = (const float*)d_in[4];
    const float* b0   = (const float*)d_in[5];
    const float* w1   = (const float*)d_in[6];
    const float* b1   = (const float*)d_in[7];
    const float* ln_g = (const float*)d_in[8];
    const float* ln_b = (const float*)d_in[9];
    float* out = (float*)d_out;

    unsigned short* wsf = (unsigned short*)d_ws;

    const size_t PART_OFF   = 262144;                 // frag region < 256 KB
    const size_t PART_BYTES = (size_t)33554432 * 2;   // 64 MB bf16 partial
    unsigned short* pw1 = (unsigned short*)((char*)d_ws + PART_OFF);
    const bool bf16p = (ws_size >= PART_OFF + PART_BYTES);

    setup_frags<<<100, 256, 0, stream>>>(wx, wy, wz, wsf);

    // 16384 lines per axis / 4 per block = 4096 blocks.
    // Single-partial schedule: axis0 stores pw1, axis1 ACCUMULATES into pw1
    // (its pw1 read is L3-hot), fused reads only pw1 -> fused's full 192 MB
    // read set (x + pw1) was touched by the immediately-preceding dispatch
    // and fits the 256 MB L3.
    if (bf16p) {
        spectral_mfma<0, 2><<<4096, 256, 0, stream>>>(x, wsf + 0 * 32768, wsf + WS_TF, wsf + WS_TI, out, pw1);
        spectral_mfma<1, 3><<<4096, 256, 0, stream>>>(x, wsf + 1 * 32768, wsf + WS_TF, wsf + WS_TI, out, pw1);
        spectral_fused<1><<<4096, 256, 0, stream>>>(x, wsf + 2 * 32768, wsf + WS_TF, wsf + WS_TI,
                                                    w0, b0, w1, b1, ln_g, ln_b, pw1, out, out);
    } else {
        spectral_mfma<0, 0><<<4096, 256, 0, stream>>>(x, wsf + 0 * 32768, wsf + WS_TF, wsf + WS_TI, out, pw1);
        spectral_mfma<1, 1><<<4096, 256, 0, stream>>>(x, wsf + 1 * 32768, wsf + WS_TF, wsf + WS_TI, out, pw1);
        spectral_fused<0><<<4096, 256, 0, stream>>>(x, wsf + 2 * 32768, wsf + WS_TF, wsf + WS_TI,
                                                    w0, b0, w1, b1, ln_g, ln_b, pw1, out, out);
    }
}